// Round 12
// baseline (288.390 us; speedup 1.0000x reference)
//
#include <hip/hip_runtime.h>
#include <cstdint>
#include <cstddef>

typedef __bf16 bf16;
typedef __attribute__((ext_vector_type(8))) __bf16 bf16x8;
typedef __attribute__((ext_vector_type(4))) __bf16 bf16x4;
typedef __attribute__((ext_vector_type(4))) float f32x4;

#define ATT_SCALE 0.125f                 // 1/sqrt(64)
#define SC_L2E    0.18033688011112042f   // ATT_SCALE * log2(e)

__device__ __forceinline__ f32x4 mfma16(bf16x8 a, bf16x8 b, f32x4 c) {
  return __builtin_amdgcn_mfma_f32_16x16x32_bf16(a, b, c, 0, 0, 0);
}

__device__ __forceinline__ void gload16(const bf16* g, bf16* l) {
  __builtin_amdgcn_global_load_lds((__attribute__((address_space(1))) void*)g,
                                   (__attribute__((address_space(3))) void*)l,
                                   16, 0, 0);
}

// ---------------- fused prep: all fp32->bf16 converts + RoPE table ----------------
__global__ __launch_bounds__(256) void prep_all(const float* __restrict__ hs,
                                                const float* __restrict__ Wq,
                                                const float* __restrict__ Wk,
                                                const float* __restrict__ Wv,
                                                const float* __restrict__ Wo,
                                                bf16* __restrict__ hs16, bf16* __restrict__ wq16,
                                                bf16* __restrict__ wk16, bf16* __restrict__ wv16,
                                                bf16* __restrict__ wo16,
                                                float* __restrict__ cosT, float* __restrict__ sinT) {
  int b = blockIdx.x, t = threadIdx.x;
  const float* src; bf16* dst; int i;
  if (b < 16384)      { src = hs; dst = hs16; i = b * 256 + t; }
  else if (b < 20480) { src = Wq; dst = wq16; i = (b - 16384) * 256 + t; }
  else if (b < 21504) { src = Wk; dst = wk16; i = (b - 20480) * 256 + t; }
  else if (b < 22528) { src = Wv; dst = wv16; i = (b - 21504) * 256 + t; }
  else if (b < 26624) { src = Wo; dst = wo16; i = (b - 22528) * 256 + t; }
  else {
    int idx = (b - 26624) * 256 + t;   // 8192*32
    int tt = idx >> 5, j = idx & 31;
    float inv = exp2f(-(float)j * (13.287712379549449f / 32.0f));
    float fr = (float)tt * inv;
    cosT[idx] = cosf(fr); sinT[idx] = sinf(fr);
    return;
  }
  float4 v = *((const float4*)src + i);
  bf16x4 o;
  o[0] = (bf16)v.x; o[1] = (bf16)v.y; o[2] = (bf16)v.z; o[3] = (bf16)v.w;
  *((bf16x4*)dst + i) = o;
}

// ---------------- QKV GEMM: 256x384 tile, grid (32,8)=256 blocks (r8/r10 winner) --
__global__ __launch_bounds__(512) void gemm_qkv(const bf16* __restrict__ A,
                                                const bf16* __restrict__ B0,
                                                const bf16* __restrict__ B1,
                                                const bf16* __restrict__ B2,
                                                bf16* __restrict__ C,
                                                const float* __restrict__ cosT,
                                                const float* __restrict__ sinT) {
  __shared__ bf16 As[3][8192];    // 16 KB per buf
  __shared__ bf16 Bs[3][12288];   // 24 KB per buf
  const int tid = threadIdx.x, lane = tid & 63, wid = tid >> 6;
  const int m0 = blockIdx.x * 256, n0 = blockIdx.y * 384;
  const int wr = wid >> 1, wc = wid & 1;
  const int fr = lane & 15, g4 = lane >> 4;
  const int sw8 = (g4 ^ ((fr >> 1) & 3)) * 8;

  f32x4 acc[4][12] = {};

  auto brow = [&](int n) -> const bf16* {
    if (n < 2048) return B0 + (size_t)n * 2048;
    if (n < 2560) return B1 + (size_t)(n - 2048) * 2048;
    return B2 + (size_t)(n - 2560) * 2048;
  };

  const int ra0 = tid >> 2, ra1 = 128 + (tid >> 2), rb2r = 256 + (tid >> 2);
  const bf16* aS0 = A + (size_t)(m0 + ra0) * 2048 + ((tid & 3) ^ ((ra0 >> 1) & 3)) * 8;
  const bf16* aS1 = A + (size_t)(m0 + ra1) * 2048 + ((tid & 3) ^ ((ra1 >> 1) & 3)) * 8;
  const bf16* bS0 = brow(n0 + ra0) + ((tid & 3) ^ ((ra0 >> 1) & 3)) * 8;
  const bf16* bS1 = brow(n0 + ra1) + ((tid & 3) ^ ((ra1 >> 1) & 3)) * 8;
  const bf16* bS2 = brow(n0 + rb2r) + ((tid & 3) ^ ((rb2r >> 1) & 3)) * 8;
  const int d0 = wid * 512, d1 = 4096 + wid * 512, d2 = 8192 + wid * 512;

#define STQA(BS, KT)  { bf16* d = &As[BS][0]; \
    gload16(aS0 + (KT) * 32, d + d0); gload16(aS1 + (KT) * 32, d + d1); }
#define STQB0(BS, KT) { bf16* d = &Bs[BS][0]; \
    gload16(bS0 + (KT) * 32, d + d0); gload16(bS1 + (KT) * 32, d + d1); }
#define STQB1(BS, KT) { gload16(bS2 + (KT) * 32, &Bs[BS][0] + d2); }

#define QTILE(KT, BI, BS, VM, STG) { \
    asm volatile("s_waitcnt vmcnt(" VM ")" ::: "memory"); \
    __builtin_amdgcn_s_barrier(); \
    __builtin_amdgcn_sched_barrier(0); \
    const bf16* Ab = &As[BI][0]; \
    const bf16* Bb = &Bs[BI][0]; \
    bf16x8 af[4], bfr[4]; \
    _Pragma("unroll") for (int mf = 0; mf < 4; ++mf) \
      af[mf] = *(const bf16x8*)(Ab + (wr * 64 + mf * 16 + fr) * 32 + sw8); \
    _Pragma("unroll") for (int q = 0; q < 4; ++q) \
      bfr[q] = *(const bf16x8*)(Bb + (wc * 192 + q * 16 + fr) * 32 + sw8); \
    if (STG) STQA(BS, (KT) + 2); \
    __builtin_amdgcn_s_setprio(1); \
    _Pragma("unroll") for (int mf = 0; mf < 4; ++mf) \
      _Pragma("unroll") for (int q = 0; q < 4; ++q) \
        acc[mf][q] = mfma16(af[mf], bfr[q], acc[mf][q]); \
    __builtin_amdgcn_s_setprio(0); \
    _Pragma("unroll") for (int q = 0; q < 4; ++q) \
      bfr[q] = *(const bf16x8*)(Bb + (wc * 192 + 64 + q * 16 + fr) * 32 + sw8); \
    if (STG) STQB0(BS, (KT) + 2); \
    __builtin_amdgcn_s_setprio(1); \
    _Pragma("unroll") for (int mf = 0; mf < 4; ++mf) \
      _Pragma("unroll") for (int q = 0; q < 4; ++q) \
        acc[mf][4 + q] = mfma16(af[mf], bfr[q], acc[mf][4 + q]); \
    __builtin_amdgcn_s_setprio(0); \
    _Pragma("unroll") for (int q = 0; q < 4; ++q) \
      bfr[q] = *(const bf16x8*)(Bb + (wc * 192 + 128 + q * 16 + fr) * 32 + sw8); \
    if (STG) STQB1(BS, (KT) + 2); \
    __builtin_amdgcn_s_setprio(1); \
    _Pragma("unroll") for (int mf = 0; mf < 4; ++mf) \
      _Pragma("unroll") for (int q = 0; q < 4; ++q) \
        acc[mf][8 + q] = mfma16(af[mf], bfr[q], acc[mf][8 + q]); \
    __builtin_amdgcn_s_setprio(0); \
  }

  STQA(0, 0); STQB0(0, 0); STQB1(0, 0);
  STQA(1, 1); STQB0(1, 1); STQB1(1, 1);

  int bi = 0, bs = 2;
  for (int kt = 0; kt < 62; ++kt) {
    QTILE(kt, bi, bs, "5", 1)
    bi = (bi == 2) ? 0 : bi + 1;
    bs = (bs == 2) ? 0 : bs + 1;
  }
  QTILE(62, bi, bs, "5", 0)
  bi = (bi == 2) ? 0 : bi + 1;
  QTILE(63, bi, bi, "0", 0)
#undef QTILE
#undef STQA
#undef STQB0
#undef STQB1

  const int fc = lane & 15, fr4 = (lane >> 4) * 4;
#pragma unroll
  for (int mf = 0; mf < 4; ++mf)
#pragma unroll
    for (int i = 0; i < 4; ++i) {
      size_t row = (size_t)(m0 + wr * 64 + mf * 16 + fr4 + i);
      bf16* base = C + row * 3072 + n0 + wc * 192;
      const float* cr = cosT + row * 32;
      const float* sr = sinT + row * 32;
#pragma unroll
      for (int g = 0; g < 3; ++g) {
        if (n0 + wc * 192 + g * 64 < 2560) {
#pragma unroll
          for (int q = 0; q < 2; ++q) {
            int j = q * 16 + fc;
            float c = cr[j], sn = sr[j];
            float x1 = acc[mf][g * 4 + q][i], x2 = acc[mf][g * 4 + q + 2][i];
            base[g * 64 + j]      = (bf16)(x1 * c - x2 * sn);
            base[g * 64 + j + 32] = (bf16)(x2 * c + x1 * sn);
          }
        } else {
#pragma unroll
          for (int q = 0; q < 4; ++q)
            base[g * 64 + q * 16 + fc] = (bf16)acc[mf][g * 4 + q][i];
        }
      }
    }
}

// ---------------- O-proj GEMM: 256x256, 4-buf, 1 barrier/K-tile (r4 winner) -------
__global__ __launch_bounds__(512, 2) void gemm_out(const bf16* __restrict__ A,
                                                   const bf16* __restrict__ B0,
                                                   float* __restrict__ Cout) {
  __shared__ bf16 As[4][8192];
  __shared__ bf16 Bs[4][8192];
  const int tid = threadIdx.x, lane = tid & 63, wid = tid >> 6;
  const int m0 = blockIdx.x * 256, n0 = blockIdx.y * 256;
  const int wr = wid >> 2, wc = wid & 3;
  const int fr = lane & 15, g4 = lane >> 4;
  const int sw8 = (g4 ^ ((fr >> 1) & 3)) * 8;
  const int K = 2048, N = 2048;

  f32x4 acc[8][4] = {};

  const bf16* aS0; const bf16* aS1; const bf16* bS0; const bf16* bS1;
  {
    int c0 = tid, r0 = c0 >> 2, l0 = (c0 & 3) ^ ((r0 >> 1) & 3);
    int c1 = 512 + tid, r1 = c1 >> 2, l1 = (c1 & 3) ^ ((r1 >> 1) & 3);
    aS0 = A + (size_t)(m0 + r0) * K + l0 * 8;
    aS1 = A + (size_t)(m0 + r1) * K + l1 * 8;
    bS0 = B0 + (size_t)(n0 + r0) * K + l0 * 8;
    bS1 = B0 + (size_t)(n0 + r1) * K + l1 * 8;
  }
  const int dst0 = wid * 512;
  const int dst1 = 4096 + wid * 512;

#define STAGE_A(KT) { bf16* d = &As[(KT) & 3][0]; \
    gload16(aS0 + (KT) * 32, d + dst0); gload16(aS1 + (KT) * 32, d + dst1); }
#define STAGE_B(KT) { bf16* d = &Bs[(KT) & 3][0]; \
    gload16(bS0 + (KT) * 32, d + dst0); gload16(bS1 + (KT) * 32, d + dst1); }

#define KTILE(KT, VM, STG) { \
    asm volatile("s_waitcnt vmcnt(" VM ")" ::: "memory"); \
    __builtin_amdgcn_s_barrier(); \
    __builtin_amdgcn_sched_barrier(0); \
    const bf16* Ab = &As[(KT) & 3][0]; \
    const bf16* Bb = &Bs[(KT) & 3][0]; \
    bf16x8 bfr[4], af[4]; \
    _Pragma("unroll") for (int nf = 0; nf < 4; ++nf) \
      bfr[nf] = *(const bf16x8*)(Bb + (wc * 64 + nf * 16 + fr) * 32 + sw8); \
    _Pragma("unroll") for (int mf = 0; mf < 4; ++mf) \
      af[mf] = *(const bf16x8*)(Ab + (wr * 128 + mf * 16 + fr) * 32 + sw8); \
    if (STG) STAGE_A((KT) + 3); \
    __builtin_amdgcn_s_setprio(1); \
    _Pragma("unroll") for (int mf = 0; mf < 4; ++mf) \
      _Pragma("unroll") for (int nf = 0; nf < 4; ++nf) \
        acc[mf][nf] = mfma16(af[mf], bfr[nf], acc[mf][nf]); \
    __builtin_amdgcn_s_setprio(0); \
    _Pragma("unroll") for (int mf = 0; mf < 4; ++mf) \
      af[mf] = *(const bf16x8*)(Ab + (wr * 128 + 64 + mf * 16 + fr) * 32 + sw8); \
    if (STG) STAGE_B((KT) + 3); \
    __builtin_amdgcn_s_setprio(1); \
    _Pragma("unroll") for (int mf = 0; mf < 4; ++mf) \
      _Pragma("unroll") for (int nf = 0; nf < 4; ++nf) \
        acc[4 + mf][nf] = mfma16(af[mf], bfr[nf], acc[4 + mf][nf]); \
    __builtin_amdgcn_s_setprio(0); \
  }

  STAGE_A(0); STAGE_B(0);
  STAGE_A(1); STAGE_B(1);
  STAGE_A(2); STAGE_B(2);

  const int NT = K >> 5;   // 64
  for (int kt = 0; kt < NT - 3; ++kt) KTILE(kt, "8", 1)
  KTILE(NT - 3, "8", 0)
  KTILE(NT - 2, "4", 0)
  KTILE(NT - 1, "0", 0)
#undef KTILE
#undef STAGE_A
#undef STAGE_B

  const int fc = lane & 15, fr4 = (lane >> 4) * 4;
#pragma unroll
  for (int am = 0; am < 8; ++am)
#pragma unroll
    for (int i = 0; i < 4; ++i) {
      size_t row = (size_t)(m0 + wr * 128 + am * 16 + fr4 + i);
#pragma unroll
      for (int nf = 0; nf < 4; ++nf) {
        int col = n0 + wc * 64 + nf * 16 + fc;
        Cout[row * (size_t)N + col] = acc[am][nf][i];
      }
    }
}

// ---------------- block-sparse attention v2 (r10 winner) + defer-max + exp2 ------
// grid (128 qblocks, 16), 512 threads = 8 waves = 2 heads x 4 rowgroups.
// Permuted-K staging: pi(p)=32*(p>>5)+((p&15)>>2)*8+((p>>4)&1)*4+(p&3) makes
// P->PV-A-operand a pure in-register cvt. Ks/Vt double-buffered, 1 barrier/step.
// NEW: exact defer-max — when __all(mx <= mrun), corr==1 exactly -> skip the
// corr exp + 4-shfl broadcast + 16-mul rescale. exp2f with folded log2(e)*scale.
__global__ __launch_bounds__(512) void attn_sparse(const bf16* __restrict__ qkv,
                                                   bf16* __restrict__ attn) {
  const int iblk = blockIdx.x;
  const int kv = blockIdx.y >> 1, pr = blockIdx.y & 1;
  const int tid = threadIdx.x, lane = tid & 63, wid = tid >> 6;
  const int h = kv * 4 + pr * 2 + (wid >> 2);
  const int rg = wid & 3;

  __shared__ bf16 Ks[2][64 * 64];   // permuted rows, XOR slot swizzle
  __shared__ bf16 Vt[2][64 * 72];   // Vt[d][key], logical order

  const int qcol = h * 64, kcol = 2048 + kv * 64, vcol = 2560 + kv * 64;
  const size_t trow0 = (size_t)iblk * 64;
  const int fr = lane & 15, g4 = lane >> 4, fk = g4 * 8, fr4 = g4 * 4;

  const bf16* qrow = qkv + (trow0 + rg * 16 + fr) * 3072 + qcol;
  bf16x8 bq0 = *(const bf16x8*)(qrow + fk);
  bf16x8 bq1 = *(const bf16x8*)(qrow + 32 + fk);

  float mrun = -INFINITY, lrun = 0.f;
  f32x4 acc[4] = {};

  const int kr = tid >> 3, ks = tid & 7;
  const int pik = ((kr >> 5) << 5) + (((kr & 15) >> 2) << 3) + (((kr >> 4) & 1) << 2) + (kr & 3);
  const int kso = ((ks ^ (kr & 7)) * 8);
  const int vp = tid & 31, vd0 = (tid >> 5) * 4;

  const int kb0m = fk, kb1m = fk + 4, kb2m = fk + 32, kb3m = fk + 36;

  const int nsel = (iblk < 8) ? (iblk + 1) : 9;
  auto jof = [&](int js) { return (iblk < 8) ? js : ((js == 0) ? 0 : iblk - 8 + js); };

  // prologue: stage K(0), V(0) into buf 0
  {
    const size_t krow = (size_t)jof(0) * 64;
    gload16(qkv + (krow + pik) * 3072 + kcol + kso, &Ks[0][0] + (tid >> 6) * 512);
    const bf16* v0p = qkv + (krow + 2 * vp) * 3072 + vcol + vd0;
    uint64_t a = *(const uint64_t*)v0p;
    uint64_t b = *(const uint64_t*)(v0p + 3072);
#pragma unroll
    for (int e = 0; e < 4; ++e) {
      uint32_t w = (uint32_t)((a >> (16 * e)) & 0xFFFF) |
                   ((uint32_t)((b >> (16 * e)) & 0xFFFF) << 16);
      *(uint32_t*)(&Vt[0][0] + (vd0 + e) * 72 + 2 * vp) = w;
    }
  }
  __syncthreads();

  for (int js = 0; js < nsel; ++js) {
    const int cur = js & 1;
    const int jblk = jof(js);
    const bool pre = (js + 1 < nsel);
    const size_t nrow = pre ? (size_t)jof(js + 1) * 64 : 0;

    // issue V(j+1) global loads early
    uint64_t va = 0, vb2 = 0;
    if (pre) {
      const bf16* v0p = qkv + (nrow + 2 * vp) * 3072 + vcol + vd0;
      va = *(const uint64_t*)v0p;
      vb2 = *(const uint64_t*)(v0p + 3072);
    }

    // S^T = K Q^T from Ks[cur]
    f32x4 s[4];
    __builtin_amdgcn_s_setprio(1);
#pragma unroll
    for (int n = 0; n < 4; ++n) {
      const char* krowp = (const char*)&Ks[cur][0] + (n * 16 + fr) * 128;
      bf16x8 ka = *(const bf16x8*)(krowp + ((g4 ^ (fr & 7)) << 4));
      bf16x8 kc = *(const bf16x8*)(krowp + (((4 + g4) ^ (fr & 7)) << 4));
      f32x4 z = {};
      z = mfma16(ka, bq0, z);
      s[n] = mfma16(kc, bq1, z);
    }
    __builtin_amdgcn_s_setprio(0);

    // stage K(j+1) -> Ks[cur^1]
    if (pre)
      gload16(qkv + (nrow + pik) * 3072 + kcol + kso, &Ks[cur ^ 1][0] + (tid >> 6) * 512);

    // causal mask (diag block only); keys are logical
    if (jblk == iblk) {
      const int qr = rg * 16 + fr;
#pragma unroll
      for (int i = 0; i < 4; ++i) {
        if (kb0m + i > qr) s[0][i] = -1e30f;
        if (kb1m + i > qr) s[1][i] = -1e30f;
        if (kb2m + i > qr) s[2][i] = -1e30f;
        if (kb3m + i > qr) s[3][i] = -1e30f;
      }
    }

    // online softmax with exact defer-max
    float t0 = fmaxf(fmaxf(s[0][0], s[0][1]), fmaxf(s[0][2], s[0][3]));
    float t1 = fmaxf(fmaxf(s[1][0], s[1][1]), fmaxf(s[1][2], s[1][3]));
    float t2 = fmaxf(fmaxf(s[2][0], s[2][1]), fmaxf(s[2][2], s[2][3]));
    float t3 = fmaxf(fmaxf(s[3][0], s[3][1]), fmaxf(s[3][2], s[3][3]));
    float mx = fmaxf(fmaxf(t0, t1), fmaxf(t2, t3));
    mx = fmaxf(mx, __shfl_xor(mx, 16, 64));
    mx = fmaxf(mx, __shfl_xor(mx, 32, 64));
    if (!__all(mx <= mrun)) {   // wave-uniform; corr==1 exactly when skipped
      float mnew = fmaxf(mrun, mx);
      float corr = exp2f((mrun - mnew) * SC_L2E);
      mrun = mnew;
      lrun *= corr;
      float cq[4];
#pragma unroll
      for (int i = 0; i < 4; ++i) cq[i] = __shfl(corr, fr4 + i, 64);
#pragma unroll
      for (int n = 0; n < 4; ++n)
#pragma unroll
        for (int i = 0; i < 4; ++i) acc[n][i] *= cq[i];
    }
    const float msc = mrun * SC_L2E;
    float ps = 0.f;
#pragma unroll
    for (int n = 0; n < 4; ++n) {
      float p0 = exp2f(fmaf(s[n][0], SC_L2E, -msc));
      float p1 = exp2f(fmaf(s[n][1], SC_L2E, -msc));
      float p2 = exp2f(fmaf(s[n][2], SC_L2E, -msc));
      float p3 = exp2f(fmaf(s[n][3], SC_L2E, -msc));
      s[n][0] = p0; s[n][1] = p1; s[n][2] = p2; s[n][3] = p3;
      ps += (p0 + p1) + (p2 + p3);
    }
    ps += __shfl_xor(ps, 16, 64);
    ps += __shfl_xor(ps, 32, 64);
    lrun += ps;

    // P -> A-operand: pure in-register cvt (permuted-key layout)
    bf16x8 pa0, pa1;
#pragma unroll
    for (int i = 0; i < 4; ++i) {
      pa0[i]     = (bf16)s[0][i];
      pa0[4 + i] = (bf16)s[1][i];
      pa1[i]     = (bf16)s[2][i];
      pa1[4 + i] = (bf16)s[3][i];
    }

    // write V(j+1) regs -> Vt[cur^1]
    if (pre) {
#pragma unroll
      for (int e = 0; e < 4; ++e) {
        uint32_t w = (uint32_t)((va >> (16 * e)) & 0xFFFF) |
                     ((uint32_t)((vb2 >> (16 * e)) & 0xFFFF) << 16);
        *(uint32_t*)(&Vt[cur ^ 1][0] + (vd0 + e) * 72 + 2 * vp) = w;
      }
    }

    // PV: O += P @ V from Vt[cur]
    __builtin_amdgcn_s_setprio(1);
#pragma unroll
    for (int n = 0; n < 4; ++n) {
      bf16x8 vb0 = *(const bf16x8*)(&Vt[cur][0] + (n * 16 + fr) * 72 + fk);
      bf16x8 vb1 = *(const bf16x8*)(&Vt[cur][0] + (n * 16 + fr) * 72 + 32 + fk);
      acc[n] = mfma16(pa0, vb0, acc[n]);
      acc[n] = mfma16(pa1, vb1, acc[n]);
    }
    __builtin_amdgcn_s_setprio(0);

    __syncthreads();   // drains K(j+1) gload_lds + Vt writes; frees bufs[cur]
  }

  // epilogue: normalize and store bf16
  float lq[4];
#pragma unroll
  for (int i = 0; i < 4; ++i) lq[i] = __shfl(lrun, fr4 + i, 64);
#pragma unroll
  for (int i = 0; i < 4; ++i) {
    float rl = 1.0f / lq[i];
    size_t t = trow0 + rg * 16 + fr4 + i;
#pragma unroll
    for (int n = 0; n < 4; ++n)
      attn[t * 2048 + h * 64 + n * 16 + fr] = (bf16)(acc[n][i] * rl);
  }
}

// ---------------- launch ----------------
extern "C" void kernel_launch(void* const* d_in, const int* in_sizes, int n_in,
                              void* d_out, int out_size, void* d_ws, size_t ws_size,
                              hipStream_t stream) {
  (void)in_sizes; (void)n_in; (void)out_size; (void)ws_size;
  const float* hs = (const float*)d_in[0];
  const float* Wq = (const float*)d_in[1];
  const float* Wk = (const float*)d_in[2];
  const float* Wv = (const float*)d_in[3];
  const float* Wo = (const float*)d_in[4];
  float* out = (float*)d_out;

  char* ws = (char*)d_ws;
  bf16* hs16 = (bf16*)(ws + 0);              // 8192*2048*2  = 33554432
  bf16* qkv  = (bf16*)(ws + 33554432);       // 8192*3072*2  = 50331648
  bf16* attn = (bf16*)(ws + 83886080);       // 8192*2048*2  = 33554432
  bf16* wq16 = (bf16*)(ws + 117440512);      // 2048*2048*2  = 8388608
  bf16* wk16 = (bf16*)(ws + 125829120);      // 512*2048*2   = 2097152
  bf16* wv16 = (bf16*)(ws + 127926272);      // 512*2048*2   = 2097152
  bf16* wo16 = (bf16*)(ws + 130023424);      // 2048*2048*2  = 8388608
  float* cosT = (float*)(ws + 138412032);    // 8192*32*4    = 1048576
  float* sinT = (float*)(ws + 139460608);    // 8192*32*4    = 1048576

  prep_all<<<27648, 256, 0, stream>>>(hs, Wq, Wk, Wv, Wo,
                                      hs16, wq16, wk16, wv16, wo16, cosT, sinT);

  // QKV projection: M=8192, N=3072, K=2048, RoPE fused; grid 256 = 1 full round
  gemm_qkv<<<dim3(32, 8), 512, 0, stream>>>(hs16, wq16, wk16, wv16, qkv, cosT, sinT);
  attn_sparse<<<dim3(128, 16), 512, 0, stream>>>(qkv, attn);
  // O projection: M=8192, N=2048, K=2048, fp32 out; grid 256 = 1 full round
  gemm_out<<<dim3(32, 8), 512, 0, stream>>>(attn, wo16, out);
}

// Round 13
// 283.860 us; speedup vs baseline: 1.0160x; 1.0160x over previous
//
#include <hip/hip_runtime.h>
#include <cstdint>
#include <cstddef>

typedef __bf16 bf16;
typedef __attribute__((ext_vector_type(8))) __bf16 bf16x8;
typedef __attribute__((ext_vector_type(4))) __bf16 bf16x4;
typedef __attribute__((ext_vector_type(4))) float f32x4;

#define ATT_SCALE 0.125f   // 1/sqrt(64)

__device__ __forceinline__ f32x4 mfma16(bf16x8 a, bf16x8 b, f32x4 c) {
  return __builtin_amdgcn_mfma_f32_16x16x32_bf16(a, b, c, 0, 0, 0);
}

__device__ __forceinline__ void gload16(const bf16* g, bf16* l) {
  __builtin_amdgcn_global_load_lds((__attribute__((address_space(1))) void*)g,
                                   (__attribute__((address_space(3))) void*)l,
                                   16, 0, 0);
}

// ---------------- fused prep: all fp32->bf16 converts + RoPE table ----------------
__global__ __launch_bounds__(256) void prep_all(const float* __restrict__ hs,
                                                const float* __restrict__ Wq,
                                                const float* __restrict__ Wk,
                                                const float* __restrict__ Wv,
                                                const float* __restrict__ Wo,
                                                bf16* __restrict__ hs16, bf16* __restrict__ wq16,
                                                bf16* __restrict__ wk16, bf16* __restrict__ wv16,
                                                bf16* __restrict__ wo16,
                                                float* __restrict__ cosT, float* __restrict__ sinT) {
  int b = blockIdx.x, t = threadIdx.x;
  const float* src; bf16* dst; int i;
  if (b < 16384)      { src = hs; dst = hs16; i = b * 256 + t; }
  else if (b < 20480) { src = Wq; dst = wq16; i = (b - 16384) * 256 + t; }
  else if (b < 21504) { src = Wk; dst = wk16; i = (b - 20480) * 256 + t; }
  else if (b < 22528) { src = Wv; dst = wv16; i = (b - 21504) * 256 + t; }
  else if (b < 26624) { src = Wo; dst = wo16; i = (b - 22528) * 256 + t; }
  else {
    int idx = (b - 26624) * 256 + t;   // 8192*32
    int tt = idx >> 5, j = idx & 31;
    float inv = exp2f(-(float)j * (13.287712379549449f / 32.0f));
    float fr = (float)tt * inv;
    cosT[idx] = cosf(fr); sinT[idx] = sinf(fr);
    return;
  }
  float4 v = *((const float4*)src + i);
  bf16x4 o;
  o[0] = (bf16)v.x; o[1] = (bf16)v.y; o[2] = (bf16)v.z; o[3] = (bf16)v.w;
  *((bf16x4*)dst + i) = o;
}

// ---------------- QKV GEMM: 256x384 tile, (2M x 4N) waves, paired RoPE frags ------
// C[m,n] = sum_k A[m,k]*B[n,k]; M=8192 N=3072 K=2048, BK=32, grid (32,8)=256.
// 512 threads = 8 waves as 2M x 4N -> per-wave 128 rows x 96 cols. LDS frag reads
// per CU per K-tile: A dup4 (64KB) + B dup2 (48KB) = 112 KB (was 128 at 4Mx2N)
// -> MfmaUtil ceiling 52% (was 45.5%). Per-wave cols = 3 RoPE PAIRS of 16-col
// frags: pair p = wc*3+pl -> head p>>1, q=p&1, fragcols c=(p>>1)*4+(p&1) and c+2
// (cols j=q*16+fc and j+32 of the head) so rotation stays in-register.
// Staging/LDS layout/ledger unchanged from r8 winner (5 loads/thread, vmcnt(5),
// chunk swizzle 0-conflict).
__global__ __launch_bounds__(512) void gemm_qkv(const bf16* __restrict__ A,
                                                const bf16* __restrict__ B0,
                                                const bf16* __restrict__ B1,
                                                const bf16* __restrict__ B2,
                                                bf16* __restrict__ C,
                                                const float* __restrict__ cosT,
                                                const float* __restrict__ sinT) {
  __shared__ bf16 As[3][8192];    // 16 KB per buf
  __shared__ bf16 Bs[3][12288];   // 24 KB per buf
  const int tid = threadIdx.x, lane = tid & 63, wid = tid >> 6;
  const int m0 = blockIdx.x * 256, n0 = blockIdx.y * 384;
  const int wr = wid >> 2, wc = wid & 3;     // 2 M-groups x 4 N-groups
  const int fr = lane & 15, g4 = lane >> 4;
  const int sw8 = (g4 ^ ((fr >> 1) & 3)) * 8;

  f32x4 acc[8][6] = {};   // 8 m-frags x (3 pairs x 2 halves)

  // B LDS row offsets (elems) for the 6 owned fragcols: j=2*pl+x -> c=(p>>1)*4+(p&1)+2x
  int boff[6];
#pragma unroll
  for (int j = 0; j < 6; ++j) {
    int p = wc * 3 + (j >> 1);
    int c = ((p >> 1) << 2) + (p & 1) + ((j & 1) << 1);
    boff[j] = c * 16 * 32;
  }

  auto brow = [&](int n) -> const bf16* {
    if (n < 2048) return B0 + (size_t)n * 2048;
    if (n < 2560) return B1 + (size_t)(n - 2048) * 2048;
    return B2 + (size_t)(n - 2560) * 2048;
  };

  const int ra0 = tid >> 2, ra1 = 128 + (tid >> 2), rb2r = 256 + (tid >> 2);
  const bf16* aS0 = A + (size_t)(m0 + ra0) * 2048 + ((tid & 3) ^ ((ra0 >> 1) & 3)) * 8;
  const bf16* aS1 = A + (size_t)(m0 + ra1) * 2048 + ((tid & 3) ^ ((ra1 >> 1) & 3)) * 8;
  const bf16* bS0 = brow(n0 + ra0) + ((tid & 3) ^ ((ra0 >> 1) & 3)) * 8;
  const bf16* bS1 = brow(n0 + ra1) + ((tid & 3) ^ ((ra1 >> 1) & 3)) * 8;
  const bf16* bS2 = brow(n0 + rb2r) + ((tid & 3) ^ ((rb2r >> 1) & 3)) * 8;
  const int d0 = wid * 512, d1 = 4096 + wid * 512, d2 = 8192 + wid * 512;

#define STQA(BS, KT)  { bf16* d = &As[BS][0]; \
    gload16(aS0 + (KT) * 32, d + d0); gload16(aS1 + (KT) * 32, d + d1); }
#define STQB0(BS, KT) { bf16* d = &Bs[BS][0]; \
    gload16(bS0 + (KT) * 32, d + d0); gload16(bS1 + (KT) * 32, d + d1); }
#define STQB1(BS, KT) { gload16(bS2 + (KT) * 32, &Bs[BS][0] + d2); }

#define QTILE(KT, BI, BS, VM, STG) { \
    asm volatile("s_waitcnt vmcnt(" VM ")" ::: "memory"); \
    __builtin_amdgcn_s_barrier(); \
    __builtin_amdgcn_sched_barrier(0); \
    const bf16* Ab = &As[BI][0]; \
    const bf16* Bb = &Bs[BI][0]; \
    bf16x8 af[8], bfr[2]; \
    _Pragma("unroll") for (int mf = 0; mf < 8; ++mf) \
      af[mf] = *(const bf16x8*)(Ab + (wr * 128 + mf * 16 + fr) * 32 + sw8); \
    bfr[0] = *(const bf16x8*)(Bb + boff[0] + fr * 32 + sw8); \
    bfr[1] = *(const bf16x8*)(Bb + boff[1] + fr * 32 + sw8); \
    if (STG) STQA(BS, (KT) + 2); \
    __builtin_amdgcn_s_setprio(1); \
    _Pragma("unroll") for (int mf = 0; mf < 8; ++mf) { \
      acc[mf][0] = mfma16(af[mf], bfr[0], acc[mf][0]); \
      acc[mf][1] = mfma16(af[mf], bfr[1], acc[mf][1]); \
    } \
    __builtin_amdgcn_s_setprio(0); \
    bfr[0] = *(const bf16x8*)(Bb + boff[2] + fr * 32 + sw8); \
    bfr[1] = *(const bf16x8*)(Bb + boff[3] + fr * 32 + sw8); \
    if (STG) STQB0(BS, (KT) + 2); \
    __builtin_amdgcn_s_setprio(1); \
    _Pragma("unroll") for (int mf = 0; mf < 8; ++mf) { \
      acc[mf][2] = mfma16(af[mf], bfr[0], acc[mf][2]); \
      acc[mf][3] = mfma16(af[mf], bfr[1], acc[mf][3]); \
    } \
    __builtin_amdgcn_s_setprio(0); \
    bfr[0] = *(const bf16x8*)(Bb + boff[4] + fr * 32 + sw8); \
    bfr[1] = *(const bf16x8*)(Bb + boff[5] + fr * 32 + sw8); \
    if (STG) STQB1(BS, (KT) + 2); \
    __builtin_amdgcn_s_setprio(1); \
    _Pragma("unroll") for (int mf = 0; mf < 8; ++mf) { \
      acc[mf][4] = mfma16(af[mf], bfr[0], acc[mf][4]); \
      acc[mf][5] = mfma16(af[mf], bfr[1], acc[mf][5]); \
    } \
    __builtin_amdgcn_s_setprio(0); \
  }

  STQA(0, 0); STQB0(0, 0); STQB1(0, 0);
  STQA(1, 1); STQB0(1, 1); STQB1(1, 1);

  int bi = 0, bs = 2;
  for (int kt = 0; kt < 62; ++kt) {
    QTILE(kt, bi, bs, "5", 1)
    bi = (bi == 2) ? 0 : bi + 1;
    bs = (bs == 2) ? 0 : bs + 1;
  }
  QTILE(62, bi, bs, "5", 0)
  bi = (bi == 2) ? 0 : bi + 1;
  QTILE(63, bi, bi, "0", 0)
#undef QTILE
#undef STQA
#undef STQB0
#undef STQB1

  // epilogue: rows m0+wr*128+mf*16+fr4+i; pair p=wc*3+pl -> head p>>1, q=p&1,
  // cols (n0 + head*64 + q*16 + fc) and +32; rotate if head is Q/K (base < 2560).
  const int fc = lane & 15, fr4 = (lane >> 4) * 4;
#pragma unroll
  for (int mf = 0; mf < 8; ++mf)
#pragma unroll
    for (int i = 0; i < 4; ++i) {
      size_t row = (size_t)(m0 + wr * 128 + mf * 16 + fr4 + i);
      const float* cr = cosT + row * 32;
      const float* sr = sinT + row * 32;
#pragma unroll
      for (int pl = 0; pl < 3; ++pl) {
        int p = wc * 3 + pl;
        int hb = n0 + (p >> 1) * 64;          // head col base
        int j = (p & 1) * 16 + fc;            // 0..31 within head
        bf16* base = C + row * 3072 + hb;
        float x1 = acc[mf][2 * pl][i], x2 = acc[mf][2 * pl + 1][i];
        if (hb < 2560) {
          float c = cr[j], sn = sr[j];
          base[j]      = (bf16)(x1 * c - x2 * sn);
          base[j + 32] = (bf16)(x2 * c + x1 * sn);
        } else {
          base[j]      = (bf16)x1;
          base[j + 32] = (bf16)x2;
        }
      }
    }
}

// ---------------- O-proj GEMM: 256x256, 4-buf, 1 barrier/K-tile (r4 winner) -------
__global__ __launch_bounds__(512, 2) void gemm_out(const bf16* __restrict__ A,
                                                   const bf16* __restrict__ B0,
                                                   float* __restrict__ Cout) {
  __shared__ bf16 As[4][8192];
  __shared__ bf16 Bs[4][8192];
  const int tid = threadIdx.x, lane = tid & 63, wid = tid >> 6;
  const int m0 = blockIdx.x * 256, n0 = blockIdx.y * 256;
  const int wr = wid >> 2, wc = wid & 3;
  const int fr = lane & 15, g4 = lane >> 4;
  const int sw8 = (g4 ^ ((fr >> 1) & 3)) * 8;
  const int K = 2048, N = 2048;

  f32x4 acc[8][4] = {};

  const bf16* aS0; const bf16* aS1; const bf16* bS0; const bf16* bS1;
  {
    int c0 = tid, r0 = c0 >> 2, l0 = (c0 & 3) ^ ((r0 >> 1) & 3);
    int c1 = 512 + tid, r1 = c1 >> 2, l1 = (c1 & 3) ^ ((r1 >> 1) & 3);
    aS0 = A + (size_t)(m0 + r0) * K + l0 * 8;
    aS1 = A + (size_t)(m0 + r1) * K + l1 * 8;
    bS0 = B0 + (size_t)(n0 + r0) * K + l0 * 8;
    bS1 = B0 + (size_t)(n0 + r1) * K + l1 * 8;
  }
  const int dst0 = wid * 512;
  const int dst1 = 4096 + wid * 512;

#define STAGE_A(KT) { bf16* d = &As[(KT) & 3][0]; \
    gload16(aS0 + (KT) * 32, d + dst0); gload16(aS1 + (KT) * 32, d + dst1); }
#define STAGE_B(KT) { bf16* d = &Bs[(KT) & 3][0]; \
    gload16(bS0 + (KT) * 32, d + dst0); gload16(bS1 + (KT) * 32, d + dst1); }

#define KTILE(KT, VM, STG) { \
    asm volatile("s_waitcnt vmcnt(" VM ")" ::: "memory"); \
    __builtin_amdgcn_s_barrier(); \
    __builtin_amdgcn_sched_barrier(0); \
    const bf16* Ab = &As[(KT) & 3][0]; \
    const bf16* Bb = &Bs[(KT) & 3][0]; \
    bf16x8 bfr[4], af[4]; \
    _Pragma("unroll") for (int nf = 0; nf < 4; ++nf) \
      bfr[nf] = *(const bf16x8*)(Bb + (wc * 64 + nf * 16 + fr) * 32 + sw8); \
    _Pragma("unroll") for (int mf = 0; mf < 4; ++mf) \
      af[mf] = *(const bf16x8*)(Ab + (wr * 128 + mf * 16 + fr) * 32 + sw8); \
    if (STG) STAGE_A((KT) + 3); \
    __builtin_amdgcn_s_setprio(1); \
    _Pragma("unroll") for (int mf = 0; mf < 4; ++mf) \
      _Pragma("unroll") for (int nf = 0; nf < 4; ++nf) \
        acc[mf][nf] = mfma16(af[mf], bfr[nf], acc[mf][nf]); \
    __builtin_amdgcn_s_setprio(0); \
    _Pragma("unroll") for (int mf = 0; mf < 4; ++mf) \
      af[mf] = *(const bf16x8*)(Ab + (wr * 128 + 64 + mf * 16 + fr) * 32 + sw8); \
    if (STG) STAGE_B((KT) + 3); \
    __builtin_amdgcn_s_setprio(1); \
    _Pragma("unroll") for (int mf = 0; mf < 4; ++mf) \
      _Pragma("unroll") for (int nf = 0; nf < 4; ++nf) \
        acc[4 + mf][nf] = mfma16(af[mf], bfr[nf], acc[4 + mf][nf]); \
    __builtin_amdgcn_s_setprio(0); \
  }

  STAGE_A(0); STAGE_B(0);
  STAGE_A(1); STAGE_B(1);
  STAGE_A(2); STAGE_B(2);

  const int NT = K >> 5;   // 64
  for (int kt = 0; kt < NT - 3; ++kt) KTILE(kt, "8", 1)
  KTILE(NT - 3, "8", 0)
  KTILE(NT - 2, "4", 0)
  KTILE(NT - 1, "0", 0)
#undef KTILE
#undef STAGE_A
#undef STAGE_B

  const int fc = lane & 15, fr4 = (lane >> 4) * 4;
#pragma unroll
  for (int am = 0; am < 8; ++am)
#pragma unroll
    for (int i = 0; i < 4; ++i) {
      size_t row = (size_t)(m0 + wr * 128 + am * 16 + fr4 + i);
#pragma unroll
      for (int nf = 0; nf < 4; ++nf) {
        int col = n0 + wc * 64 + nf * 16 + fc;
        Cout[row * (size_t)N + col] = acc[am][nf][i];
      }
    }
}

// ---------------- block-sparse attention v2 (r10 winner, verbatim) ---------------
__global__ __launch_bounds__(512) void attn_sparse(const bf16* __restrict__ qkv,
                                                   bf16* __restrict__ attn) {
  const int iblk = blockIdx.x;
  const int kv = blockIdx.y >> 1, pr = blockIdx.y & 1;
  const int tid = threadIdx.x, lane = tid & 63, wid = tid >> 6;
  const int h = kv * 4 + pr * 2 + (wid >> 2);
  const int rg = wid & 3;

  __shared__ bf16 Ks[2][64 * 64];   // permuted rows, XOR slot swizzle
  __shared__ bf16 Vt[2][64 * 72];   // Vt[d][key], logical order

  const int qcol = h * 64, kcol = 2048 + kv * 64, vcol = 2560 + kv * 64;
  const size_t trow0 = (size_t)iblk * 64;
  const int fr = lane & 15, g4 = lane >> 4, fk = g4 * 8, fr4 = g4 * 4;

  const bf16* qrow = qkv + (trow0 + rg * 16 + fr) * 3072 + qcol;
  bf16x8 bq0 = *(const bf16x8*)(qrow + fk);
  bf16x8 bq1 = *(const bf16x8*)(qrow + 32 + fk);

  float mrun = -INFINITY, lrun = 0.f;
  f32x4 acc[4] = {};

  const int kr = tid >> 3, ks = tid & 7;
  const int pik = ((kr >> 5) << 5) + (((kr & 15) >> 2) << 3) + (((kr >> 4) & 1) << 2) + (kr & 3);
  const int kso = ((ks ^ (kr & 7)) * 8);
  const int vp = tid & 31, vd0 = (tid >> 5) * 4;

  const int kb0m = fk, kb1m = fk + 4, kb2m = fk + 32, kb3m = fk + 36;

  const int nsel = (iblk < 8) ? (iblk + 1) : 9;
  auto jof = [&](int js) { return (iblk < 8) ? js : ((js == 0) ? 0 : iblk - 8 + js); };

  // prologue: stage K(0), V(0) into buf 0
  {
    const size_t krow = (size_t)jof(0) * 64;
    gload16(qkv + (krow + pik) * 3072 + kcol + kso, &Ks[0][0] + (tid >> 6) * 512);
    const bf16* v0p = qkv + (krow + 2 * vp) * 3072 + vcol + vd0;
    uint64_t a = *(const uint64_t*)v0p;
    uint64_t b = *(const uint64_t*)(v0p + 3072);
#pragma unroll
    for (int e = 0; e < 4; ++e) {
      uint32_t w = (uint32_t)((a >> (16 * e)) & 0xFFFF) |
                   ((uint32_t)((b >> (16 * e)) & 0xFFFF) << 16);
      *(uint32_t*)(&Vt[0][0] + (vd0 + e) * 72 + 2 * vp) = w;
    }
  }
  __syncthreads();

  for (int js = 0; js < nsel; ++js) {
    const int cur = js & 1;
    const int jblk = jof(js);
    const bool pre = (js + 1 < nsel);
    const size_t nrow = pre ? (size_t)jof(js + 1) * 64 : 0;

    // issue V(j+1) global loads early
    uint64_t va = 0, vb2 = 0;
    if (pre) {
      const bf16* v0p = qkv + (nrow + 2 * vp) * 3072 + vcol + vd0;
      va = *(const uint64_t*)v0p;
      vb2 = *(const uint64_t*)(v0p + 3072);
    }

    // S^T = K Q^T from Ks[cur]
    f32x4 s[4];
    __builtin_amdgcn_s_setprio(1);
#pragma unroll
    for (int n = 0; n < 4; ++n) {
      const char* krowp = (const char*)&Ks[cur][0] + (n * 16 + fr) * 128;
      bf16x8 ka = *(const bf16x8*)(krowp + ((g4 ^ (fr & 7)) << 4));
      bf16x8 kc = *(const bf16x8*)(krowp + (((4 + g4) ^ (fr & 7)) << 4));
      f32x4 z = {};
      z = mfma16(ka, bq0, z);
      s[n] = mfma16(kc, bq1, z);
    }
    __builtin_amdgcn_s_setprio(0);

    // stage K(j+1) -> Ks[cur^1]
    if (pre)
      gload16(qkv + (nrow + pik) * 3072 + kcol + kso, &Ks[cur ^ 1][0] + (tid >> 6) * 512);

    // causal mask (diag block only); keys are logical
    if (jblk == iblk) {
      const int qr = rg * 16 + fr;
#pragma unroll
      for (int i = 0; i < 4; ++i) {
        if (kb0m + i > qr) s[0][i] = -1e30f;
        if (kb1m + i > qr) s[1][i] = -1e30f;
        if (kb2m + i > qr) s[2][i] = -1e30f;
        if (kb3m + i > qr) s[3][i] = -1e30f;
      }
    }

    // online softmax (scale folded into exp)
    float t0 = fmaxf(fmaxf(s[0][0], s[0][1]), fmaxf(s[0][2], s[0][3]));
    float t1 = fmaxf(fmaxf(s[1][0], s[1][1]), fmaxf(s[1][2], s[1][3]));
    float t2 = fmaxf(fmaxf(s[2][0], s[2][1]), fmaxf(s[2][2], s[2][3]));
    float t3 = fmaxf(fmaxf(s[3][0], s[3][1]), fmaxf(s[3][2], s[3][3]));
    float mx = fmaxf(fmaxf(t0, t1), fmaxf(t2, t3));
    mx = fmaxf(mx, __shfl_xor(mx, 16, 64));
    mx = fmaxf(mx, __shfl_xor(mx, 32, 64));
    float mnew = fmaxf(mrun, mx);
    float corr = __expf((mrun - mnew) * ATT_SCALE);
    mrun = mnew;
    const float msc = mnew * ATT_SCALE;
    float ps = 0.f;
#pragma unroll
    for (int n = 0; n < 4; ++n) {
      float p0 = __expf(fmaf(s[n][0], ATT_SCALE, -msc));
      float p1 = __expf(fmaf(s[n][1], ATT_SCALE, -msc));
      float p2 = __expf(fmaf(s[n][2], ATT_SCALE, -msc));
      float p3 = __expf(fmaf(s[n][3], ATT_SCALE, -msc));
      s[n][0] = p0; s[n][1] = p1; s[n][2] = p2; s[n][3] = p3;
      ps += (p0 + p1) + (p2 + p3);
    }
    ps += __shfl_xor(ps, 16, 64);
    ps += __shfl_xor(ps, 32, 64);
    lrun = lrun * corr + ps;

    float cq[4];
#pragma unroll
    for (int i = 0; i < 4; ++i) cq[i] = __shfl(corr, fr4 + i, 64);
#pragma unroll
    for (int n = 0; n < 4; ++n)
#pragma unroll
      for (int i = 0; i < 4; ++i) acc[n][i] *= cq[i];

    // P -> A-operand: pure in-register cvt (permuted-key layout)
    bf16x8 pa0, pa1;
#pragma unroll
    for (int i = 0; i < 4; ++i) {
      pa0[i]     = (bf16)s[0][i];
      pa0[4 + i] = (bf16)s[1][i];
      pa1[i]     = (bf16)s[2][i];
      pa1[4 + i] = (bf16)s[3][i];
    }

    // write V(j+1) regs -> Vt[cur^1]
    if (pre) {
#pragma unroll
      for (int e = 0; e < 4; ++e) {
        uint32_t w = (uint32_t)((va >> (16 * e)) & 0xFFFF) |
                     ((uint32_t)((vb2 >> (16 * e)) & 0xFFFF) << 16);
        *(uint32_t*)(&Vt[cur ^ 1][0] + (vd0 + e) * 72 + 2 * vp) = w;
      }
    }

    // PV: O += P @ V from Vt[cur]
    __builtin_amdgcn_s_setprio(1);
#pragma unroll
    for (int n = 0; n < 4; ++n) {
      bf16x8 vb0 = *(const bf16x8*)(&Vt[cur][0] + (n * 16 + fr) * 72 + fk);
      bf16x8 vb1 = *(const bf16x8*)(&Vt[cur][0] + (n * 16 + fr) * 72 + 32 + fk);
      acc[n] = mfma16(pa0, vb0, acc[n]);
      acc[n] = mfma16(pa1, vb1, acc[n]);
    }
    __builtin_amdgcn_s_setprio(0);

    __syncthreads();   // drains K(j+1) gload_lds + Vt writes; frees bufs[cur]
  }

  // epilogue: normalize and store bf16
  float lq[4];
#pragma unroll
  for (int i = 0; i < 4; ++i) lq[i] = __shfl(lrun, fr4 + i, 64);
#pragma unroll
  for (int i = 0; i < 4; ++i) {
    float rl = 1.0f / lq[i];
    size_t t = trow0 + rg * 16 + fr4 + i;
#pragma unroll
    for (int n = 0; n < 4; ++n)
      attn[t * 2048 + h * 64 + n * 16 + fr] = (bf16)(acc[n][i] * rl);
  }
}

// ---------------- launch ----------------
extern "C" void kernel_launch(void* const* d_in, const int* in_sizes, int n_in,
                              void* d_out, int out_size, void* d_ws, size_t ws_size,
                              hipStream_t stream) {
  (void)in_sizes; (void)n_in; (void)out_size; (void)ws_size;
  const float* hs = (const float*)d_in[0];
  const float* Wq = (const float*)d_in[1];
  const float* Wk = (const float*)d_in[2];
  const float* Wv = (const float*)d_in[3];
  const float* Wo = (const float*)d_in[4];
  float* out = (float*)d_out;

  char* ws = (char*)d_ws;
  bf16* hs16 = (bf16*)(ws + 0);              // 8192*2048*2  = 33554432
  bf16* qkv  = (bf16*)(ws + 33554432);       // 8192*3072*2  = 50331648
  bf16* attn = (bf16*)(ws + 83886080);       // 8192*2048*2  = 33554432
  bf16* wq16 = (bf16*)(ws + 117440512);      // 2048*2048*2  = 8388608
  bf16* wk16 = (bf16*)(ws + 125829120);      // 512*2048*2   = 2097152
  bf16* wv16 = (bf16*)(ws + 127926272);      // 512*2048*2   = 2097152
  bf16* wo16 = (bf16*)(ws + 130023424);      // 2048*2048*2  = 8388608
  float* cosT = (float*)(ws + 138412032);    // 8192*32*4    = 1048576
  float* sinT = (float*)(ws + 139460608);    // 8192*32*4    = 1048576

  prep_all<<<27648, 256, 0, stream>>>(hs, Wq, Wk, Wv, Wo,
                                      hs16, wq16, wk16, wv16, wo16, cosT, sinT);

  // QKV projection: M=8192, N=3072, K=2048, RoPE fused; grid 256 = 1 full round
  gemm_qkv<<<dim3(32, 8), 512, 0, stream>>>(hs16, wq16, wk16, wv16, qkv, cosT, sinT);
  attn_sparse<<<dim3(128, 16), 512, 0, stream>>>(qkv, attn);
  // O projection: M=8192, N=2048, K=2048, fp32 out; grid 256 = 1 full round
  gemm_out<<<dim3(32, 8), 512, 0, stream>>>(attn, wo16, out);
}

// Round 14
// 267.510 us; speedup vs baseline: 1.0781x; 1.0611x over previous
//
#include <hip/hip_runtime.h>
#include <cstdint>
#include <cstddef>

typedef __bf16 bf16;
typedef __attribute__((ext_vector_type(8))) __bf16 bf16x8;
typedef __attribute__((ext_vector_type(4))) __bf16 bf16x4;
typedef __attribute__((ext_vector_type(4))) float f32x4;

#define ATT_SCALE 0.125f   // 1/sqrt(64)

__device__ __forceinline__ f32x4 mfma16(bf16x8 a, bf16x8 b, f32x4 c) {
  return __builtin_amdgcn_mfma_f32_16x16x32_bf16(a, b, c, 0, 0, 0);
}

__device__ __forceinline__ void gload16(const bf16* g, bf16* l) {
  __builtin_amdgcn_global_load_lds((__attribute__((address_space(1))) void*)g,
                                   (__attribute__((address_space(3))) void*)l,
                                   16, 0, 0);
}

// ---------------- fused prep: all fp32->bf16 converts + RoPE table ----------------
__global__ __launch_bounds__(256) void prep_all(const float* __restrict__ hs,
                                                const float* __restrict__ Wq,
                                                const float* __restrict__ Wk,
                                                const float* __restrict__ Wv,
                                                const float* __restrict__ Wo,
                                                bf16* __restrict__ hs16, bf16* __restrict__ wq16,
                                                bf16* __restrict__ wk16, bf16* __restrict__ wv16,
                                                bf16* __restrict__ wo16,
                                                float* __restrict__ cosT, float* __restrict__ sinT) {
  int b = blockIdx.x, t = threadIdx.x;
  const float* src; bf16* dst; int i;
  if (b < 16384)      { src = hs; dst = hs16; i = b * 256 + t; }
  else if (b < 20480) { src = Wq; dst = wq16; i = (b - 16384) * 256 + t; }
  else if (b < 21504) { src = Wk; dst = wk16; i = (b - 20480) * 256 + t; }
  else if (b < 22528) { src = Wv; dst = wv16; i = (b - 21504) * 256 + t; }
  else if (b < 26624) { src = Wo; dst = wo16; i = (b - 22528) * 256 + t; }
  else {
    int idx = (b - 26624) * 256 + t;   // 8192*32
    int tt = idx >> 5, j = idx & 31;
    float inv = exp2f(-(float)j * (13.287712379549449f / 32.0f));
    float fr = (float)tt * inv;
    cosT[idx] = cosf(fr); sinT[idx] = sinf(fr);
    return;
  }
  float4 v = *((const float4*)src + i);
  bf16x4 o;
  o[0] = (bf16)v.x; o[1] = (bf16)v.y; o[2] = (bf16)v.z; o[3] = (bf16)v.w;
  *((bf16x4*)dst + i) = o;
}

// ---------------- QKV GEMM: 256x384 tile, grid (32,8)=256 blocks (r8/r10 winner) --
__global__ __launch_bounds__(512) void gemm_qkv(const bf16* __restrict__ A,
                                                const bf16* __restrict__ B0,
                                                const bf16* __restrict__ B1,
                                                const bf16* __restrict__ B2,
                                                bf16* __restrict__ C,
                                                const float* __restrict__ cosT,
                                                const float* __restrict__ sinT) {
  __shared__ bf16 As[3][8192];    // 16 KB per buf
  __shared__ bf16 Bs[3][12288];   // 24 KB per buf
  const int tid = threadIdx.x, lane = tid & 63, wid = tid >> 6;
  const int m0 = blockIdx.x * 256, n0 = blockIdx.y * 384;
  const int wr = wid >> 1, wc = wid & 1;
  const int fr = lane & 15, g4 = lane >> 4;
  const int sw8 = (g4 ^ ((fr >> 1) & 3)) * 8;

  f32x4 acc[4][12] = {};

  auto brow = [&](int n) -> const bf16* {
    if (n < 2048) return B0 + (size_t)n * 2048;
    if (n < 2560) return B1 + (size_t)(n - 2048) * 2048;
    return B2 + (size_t)(n - 2560) * 2048;
  };

  const int ra0 = tid >> 2, ra1 = 128 + (tid >> 2), rb2r = 256 + (tid >> 2);
  const bf16* aS0 = A + (size_t)(m0 + ra0) * 2048 + ((tid & 3) ^ ((ra0 >> 1) & 3)) * 8;
  const bf16* aS1 = A + (size_t)(m0 + ra1) * 2048 + ((tid & 3) ^ ((ra1 >> 1) & 3)) * 8;
  const bf16* bS0 = brow(n0 + ra0) + ((tid & 3) ^ ((ra0 >> 1) & 3)) * 8;
  const bf16* bS1 = brow(n0 + ra1) + ((tid & 3) ^ ((ra1 >> 1) & 3)) * 8;
  const bf16* bS2 = brow(n0 + rb2r) + ((tid & 3) ^ ((rb2r >> 1) & 3)) * 8;
  const int d0 = wid * 512, d1 = 4096 + wid * 512, d2 = 8192 + wid * 512;

#define STQA(BS, KT)  { bf16* d = &As[BS][0]; \
    gload16(aS0 + (KT) * 32, d + d0); gload16(aS1 + (KT) * 32, d + d1); }
#define STQB0(BS, KT) { bf16* d = &Bs[BS][0]; \
    gload16(bS0 + (KT) * 32, d + d0); gload16(bS1 + (KT) * 32, d + d1); }
#define STQB1(BS, KT) { gload16(bS2 + (KT) * 32, &Bs[BS][0] + d2); }

#define QTILE(KT, BI, BS, VM, STG) { \
    asm volatile("s_waitcnt vmcnt(" VM ")" ::: "memory"); \
    __builtin_amdgcn_s_barrier(); \
    __builtin_amdgcn_sched_barrier(0); \
    const bf16* Ab = &As[BI][0]; \
    const bf16* Bb = &Bs[BI][0]; \
    bf16x8 af[4], bfr[4]; \
    _Pragma("unroll") for (int mf = 0; mf < 4; ++mf) \
      af[mf] = *(const bf16x8*)(Ab + (wr * 64 + mf * 16 + fr) * 32 + sw8); \
    _Pragma("unroll") for (int q = 0; q < 4; ++q) \
      bfr[q] = *(const bf16x8*)(Bb + (wc * 192 + q * 16 + fr) * 32 + sw8); \
    if (STG) STQA(BS, (KT) + 2); \
    __builtin_amdgcn_s_setprio(1); \
    _Pragma("unroll") for (int mf = 0; mf < 4; ++mf) \
      _Pragma("unroll") for (int q = 0; q < 4; ++q) \
        acc[mf][q] = mfma16(af[mf], bfr[q], acc[mf][q]); \
    __builtin_amdgcn_s_setprio(0); \
    _Pragma("unroll") for (int q = 0; q < 4; ++q) \
      bfr[q] = *(const bf16x8*)(Bb + (wc * 192 + 64 + q * 16 + fr) * 32 + sw8); \
    if (STG) STQB0(BS, (KT) + 2); \
    __builtin_amdgcn_s_setprio(1); \
    _Pragma("unroll") for (int mf = 0; mf < 4; ++mf) \
      _Pragma("unroll") for (int q = 0; q < 4; ++q) \
        acc[mf][4 + q] = mfma16(af[mf], bfr[q], acc[mf][4 + q]); \
    __builtin_amdgcn_s_setprio(0); \
    _Pragma("unroll") for (int q = 0; q < 4; ++q) \
      bfr[q] = *(const bf16x8*)(Bb + (wc * 192 + 128 + q * 16 + fr) * 32 + sw8); \
    if (STG) STQB1(BS, (KT) + 2); \
    __builtin_amdgcn_s_setprio(1); \
    _Pragma("unroll") for (int mf = 0; mf < 4; ++mf) \
      _Pragma("unroll") for (int q = 0; q < 4; ++q) \
        acc[mf][8 + q] = mfma16(af[mf], bfr[q], acc[mf][8 + q]); \
    __builtin_amdgcn_s_setprio(0); \
  }

  STQA(0, 0); STQB0(0, 0); STQB1(0, 0);
  STQA(1, 1); STQB0(1, 1); STQB1(1, 1);

  int bi = 0, bs = 2;
  for (int kt = 0; kt < 62; ++kt) {
    QTILE(kt, bi, bs, "5", 1)
    bi = (bi == 2) ? 0 : bi + 1;
    bs = (bs == 2) ? 0 : bs + 1;
  }
  QTILE(62, bi, bs, "5", 0)
  bi = (bi == 2) ? 0 : bi + 1;
  QTILE(63, bi, bi, "0", 0)
#undef QTILE
#undef STQA
#undef STQB0
#undef STQB1

  const int fc = lane & 15, fr4 = (lane >> 4) * 4;
#pragma unroll
  for (int mf = 0; mf < 4; ++mf)
#pragma unroll
    for (int i = 0; i < 4; ++i) {
      size_t row = (size_t)(m0 + wr * 64 + mf * 16 + fr4 + i);
      bf16* base = C + row * 3072 + n0 + wc * 192;
      const float* cr = cosT + row * 32;
      const float* sr = sinT + row * 32;
#pragma unroll
      for (int g = 0; g < 3; ++g) {
        if (n0 + wc * 192 + g * 64 < 2560) {
#pragma unroll
          for (int q = 0; q < 2; ++q) {
            int j = q * 16 + fc;
            float c = cr[j], sn = sr[j];
            float x1 = acc[mf][g * 4 + q][i], x2 = acc[mf][g * 4 + q + 2][i];
            base[g * 64 + j]      = (bf16)(x1 * c - x2 * sn);
            base[g * 64 + j + 32] = (bf16)(x2 * c + x1 * sn);
          }
        } else {
#pragma unroll
          for (int q = 0; q < 4; ++q)
            base[g * 64 + q * 16 + fc] = (bf16)acc[mf][g * 4 + q][i];
        }
      }
    }
}

// ---------------- O-proj GEMM: 256x256, 4-buf, 1 barrier/K-tile (r4 winner) -------
__global__ __launch_bounds__(512, 2) void gemm_out(const bf16* __restrict__ A,
                                                   const bf16* __restrict__ B0,
                                                   float* __restrict__ Cout) {
  __shared__ bf16 As[4][8192];
  __shared__ bf16 Bs[4][8192];
  const int tid = threadIdx.x, lane = tid & 63, wid = tid >> 6;
  const int m0 = blockIdx.x * 256, n0 = blockIdx.y * 256;
  const int wr = wid >> 2, wc = wid & 3;
  const int fr = lane & 15, g4 = lane >> 4;
  const int sw8 = (g4 ^ ((fr >> 1) & 3)) * 8;
  const int K = 2048, N = 2048;

  f32x4 acc[8][4] = {};

  const bf16* aS0; const bf16* aS1; const bf16* bS0; const bf16* bS1;
  {
    int c0 = tid, r0 = c0 >> 2, l0 = (c0 & 3) ^ ((r0 >> 1) & 3);
    int c1 = 512 + tid, r1 = c1 >> 2, l1 = (c1 & 3) ^ ((r1 >> 1) & 3);
    aS0 = A + (size_t)(m0 + r0) * K + l0 * 8;
    aS1 = A + (size_t)(m0 + r1) * K + l1 * 8;
    bS0 = B0 + (size_t)(n0 + r0) * K + l0 * 8;
    bS1 = B0 + (size_t)(n0 + r1) * K + l1 * 8;
  }
  const int dst0 = wid * 512;
  const int dst1 = 4096 + wid * 512;

#define STAGE_A(KT) { bf16* d = &As[(KT) & 3][0]; \
    gload16(aS0 + (KT) * 32, d + dst0); gload16(aS1 + (KT) * 32, d + dst1); }
#define STAGE_B(KT) { bf16* d = &Bs[(KT) & 3][0]; \
    gload16(bS0 + (KT) * 32, d + dst0); gload16(bS1 + (KT) * 32, d + dst1); }

#define KTILE(KT, VM, STG) { \
    asm volatile("s_waitcnt vmcnt(" VM ")" ::: "memory"); \
    __builtin_amdgcn_s_barrier(); \
    __builtin_amdgcn_sched_barrier(0); \
    const bf16* Ab = &As[(KT) & 3][0]; \
    const bf16* Bb = &Bs[(KT) & 3][0]; \
    bf16x8 bfr[4], af[4]; \
    _Pragma("unroll") for (int nf = 0; nf < 4; ++nf) \
      bfr[nf] = *(const bf16x8*)(Bb + (wc * 64 + nf * 16 + fr) * 32 + sw8); \
    _Pragma("unroll") for (int mf = 0; mf < 4; ++mf) \
      af[mf] = *(const bf16x8*)(Ab + (wr * 128 + mf * 16 + fr) * 32 + sw8); \
    if (STG) STAGE_A((KT) + 3); \
    __builtin_amdgcn_s_setprio(1); \
    _Pragma("unroll") for (int mf = 0; mf < 4; ++mf) \
      _Pragma("unroll") for (int nf = 0; nf < 4; ++nf) \
        acc[mf][nf] = mfma16(af[mf], bfr[nf], acc[mf][nf]); \
    __builtin_amdgcn_s_setprio(0); \
    _Pragma("unroll") for (int mf = 0; mf < 4; ++mf) \
      af[mf] = *(const bf16x8*)(Ab + (wr * 128 + 64 + mf * 16 + fr) * 32 + sw8); \
    if (STG) STAGE_B((KT) + 3); \
    __builtin_amdgcn_s_setprio(1); \
    _Pragma("unroll") for (int mf = 0; mf < 4; ++mf) \
      _Pragma("unroll") for (int nf = 0; nf < 4; ++nf) \
        acc[4 + mf][nf] = mfma16(af[mf], bfr[nf], acc[4 + mf][nf]); \
    __builtin_amdgcn_s_setprio(0); \
  }

  STAGE_A(0); STAGE_B(0);
  STAGE_A(1); STAGE_B(1);
  STAGE_A(2); STAGE_B(2);

  const int NT = K >> 5;   // 64
  for (int kt = 0; kt < NT - 3; ++kt) KTILE(kt, "8", 1)
  KTILE(NT - 3, "8", 0)
  KTILE(NT - 2, "4", 0)
  KTILE(NT - 1, "0", 0)
#undef KTILE
#undef STAGE_A
#undef STAGE_B

  const int fc = lane & 15, fr4 = (lane >> 4) * 4;
#pragma unroll
  for (int am = 0; am < 8; ++am)
#pragma unroll
    for (int i = 0; i < 4; ++i) {
      size_t row = (size_t)(m0 + wr * 128 + am * 16 + fr4 + i);
#pragma unroll
      for (int nf = 0; nf < 4; ++nf) {
        int col = n0 + wc * 64 + nf * 16 + fc;
        Cout[row * (size_t)N + col] = acc[am][nf][i];
      }
    }
}

// ---------------- block-sparse attention v2: permuted-key, no P round-trip --------
// grid (128 qblocks, 16), 512 threads = 8 waves = 2 heads x 4 rowgroups.
// K staged in PERMUTED row order pi(p)=32*(p>>5)+((p&15)>>2)*8+((p>>4)&1)*4+(p&3)
// so QK^T output slots {s[0],s[1]} are exactly PV's pa0 keys and {s[2],s[3]} pa1:
// P->A-operand is a pure in-register bf16 cvt. V staged logically.
// Ks and Vt double-buffered -> ONE __syncthreads per KV step. LDS 34 KB.
__global__ __launch_bounds__(512) void attn_sparse(const bf16* __restrict__ qkv,
                                                   bf16* __restrict__ attn) {
  const int iblk = blockIdx.x;
  const int kv = blockIdx.y >> 1, pr = blockIdx.y & 1;
  const int tid = threadIdx.x, lane = tid & 63, wid = tid >> 6;
  const int h = kv * 4 + pr * 2 + (wid >> 2);
  const int rg = wid & 3;

  __shared__ bf16 Ks[2][64 * 64];   // permuted rows, XOR slot swizzle
  __shared__ bf16 Vt[2][64 * 72];   // Vt[d][key], logical order

  const int qcol = h * 64, kcol = 2048 + kv * 64, vcol = 2560 + kv * 64;
  const size_t trow0 = (size_t)iblk * 64;
  const int fr = lane & 15, g4 = lane >> 4, fk = g4 * 8, fr4 = g4 * 4;

  const bf16* qrow = qkv + (trow0 + rg * 16 + fr) * 3072 + qcol;
  bf16x8 bq0 = *(const bf16x8*)(qrow + fk);
  bf16x8 bq1 = *(const bf16x8*)(qrow + 32 + fk);

  float mrun = -INFINITY, lrun = 0.f;
  f32x4 acc[4] = {};

  const int kr = tid >> 3, ks = tid & 7;
  const int pik = ((kr >> 5) << 5) + (((kr & 15) >> 2) << 3) + (((kr >> 4) & 1) << 2) + (kr & 3);
  const int kso = ((ks ^ (kr & 7)) * 8);
  const int vp = tid & 31, vd0 = (tid >> 5) * 4;

  const int kb0m = fk, kb1m = fk + 4, kb2m = fk + 32, kb3m = fk + 36;

  const int nsel = (iblk < 8) ? (iblk + 1) : 9;
  auto jof = [&](int js) { return (iblk < 8) ? js : ((js == 0) ? 0 : iblk - 8 + js); };

  // prologue: stage K(0), V(0) into buf 0
  {
    const size_t krow = (size_t)jof(0) * 64;
    gload16(qkv + (krow + pik) * 3072 + kcol + kso, &Ks[0][0] + (tid >> 6) * 512);
    const bf16* v0p = qkv + (krow + 2 * vp) * 3072 + vcol + vd0;
    uint64_t a = *(const uint64_t*)v0p;
    uint64_t b = *(const uint64_t*)(v0p + 3072);
#pragma unroll
    for (int e = 0; e < 4; ++e) {
      uint32_t w = (uint32_t)((a >> (16 * e)) & 0xFFFF) |
                   ((uint32_t)((b >> (16 * e)) & 0xFFFF) << 16);
      *(uint32_t*)(&Vt[0][0] + (vd0 + e) * 72 + 2 * vp) = w;
    }
  }
  __syncthreads();

  for (int js = 0; js < nsel; ++js) {
    const int cur = js & 1;
    const int jblk = jof(js);
    const bool pre = (js + 1 < nsel);
    const size_t nrow = pre ? (size_t)jof(js + 1) * 64 : 0;

    // issue V(j+1) global loads early — latency hides under QK^T/softmax
    uint64_t va = 0, vb2 = 0;
    if (pre) {
      const bf16* v0p = qkv + (nrow + 2 * vp) * 3072 + vcol + vd0;
      va = *(const uint64_t*)v0p;
      vb2 = *(const uint64_t*)(v0p + 3072);
    }

    // S^T = K Q^T from Ks[cur] (physical rows; lane -> 16 scores of q-row fr)
    f32x4 s[4];
    __builtin_amdgcn_s_setprio(1);
#pragma unroll
    for (int n = 0; n < 4; ++n) {
      const char* krowp = (const char*)&Ks[cur][0] + (n * 16 + fr) * 128;
      bf16x8 ka = *(const bf16x8*)(krowp + ((g4 ^ (fr & 7)) << 4));
      bf16x8 kc = *(const bf16x8*)(krowp + (((4 + g4) ^ (fr & 7)) << 4));
      f32x4 z = {};
      z = mfma16(ka, bq0, z);
      s[n] = mfma16(kc, bq1, z);
    }
    __builtin_amdgcn_s_setprio(0);

    // stage K(j+1) -> Ks[cur^1] (WAR-safe: last read in js-1, behind prev barrier)
    if (pre)
      gload16(qkv + (nrow + pik) * 3072 + kcol + kso, &Ks[cur ^ 1][0] + (tid >> 6) * 512);

    // causal mask (diag block only), raw scores; keys are logical
    if (jblk == iblk) {
      const int qr = rg * 16 + fr;
#pragma unroll
      for (int i = 0; i < 4; ++i) {
        if (kb0m + i > qr) s[0][i] = -1e30f;
        if (kb1m + i > qr) s[1][i] = -1e30f;
        if (kb2m + i > qr) s[2][i] = -1e30f;
        if (kb3m + i > qr) s[3][i] = -1e30f;
      }
    }

    // online softmax (scale folded into exp)
    float t0 = fmaxf(fmaxf(s[0][0], s[0][1]), fmaxf(s[0][2], s[0][3]));
    float t1 = fmaxf(fmaxf(s[1][0], s[1][1]), fmaxf(s[1][2], s[1][3]));
    float t2 = fmaxf(fmaxf(s[2][0], s[2][1]), fmaxf(s[2][2], s[2][3]));
    float t3 = fmaxf(fmaxf(s[3][0], s[3][1]), fmaxf(s[3][2], s[3][3]));
    float mx = fmaxf(fmaxf(t0, t1), fmaxf(t2, t3));
    mx = fmaxf(mx, __shfl_xor(mx, 16, 64));
    mx = fmaxf(mx, __shfl_xor(mx, 32, 64));
    float mnew = fmaxf(mrun, mx);
    float corr = __expf((mrun - mnew) * ATT_SCALE);
    mrun = mnew;
    const float msc = mnew * ATT_SCALE;
    float ps = 0.f;
#pragma unroll
    for (int n = 0; n < 4; ++n) {
      float p0 = __expf(fmaf(s[n][0], ATT_SCALE, -msc));
      float p1 = __expf(fmaf(s[n][1], ATT_SCALE, -msc));
      float p2 = __expf(fmaf(s[n][2], ATT_SCALE, -msc));
      float p3 = __expf(fmaf(s[n][3], ATT_SCALE, -msc));
      s[n][0] = p0; s[n][1] = p1; s[n][2] = p2; s[n][3] = p3;
      ps += (p0 + p1) + (p2 + p3);
    }
    ps += __shfl_xor(ps, 16, 64);
    ps += __shfl_xor(ps, 32, 64);
    lrun = lrun * corr + ps;

    float cq[4];
#pragma unroll
    for (int i = 0; i < 4; ++i) cq[i] = __shfl(corr, fr4 + i, 64);
#pragma unroll
    for (int n = 0; n < 4; ++n)
#pragma unroll
      for (int i = 0; i < 4; ++i) acc[n][i] *= cq[i];

    // P -> A-operand: pure in-register cvt (permuted-key layout)
    bf16x8 pa0, pa1;
#pragma unroll
    for (int i = 0; i < 4; ++i) {
      pa0[i]     = (bf16)s[0][i];
      pa0[4 + i] = (bf16)s[1][i];
      pa1[i]     = (bf16)s[2][i];
      pa1[4 + i] = (bf16)s[3][i];
    }

    // write V(j+1) regs -> Vt[cur^1] (late write; WAR-safe behind prev barrier)
    if (pre) {
#pragma unroll
      for (int e = 0; e < 4; ++e) {
        uint32_t w = (uint32_t)((va >> (16 * e)) & 0xFFFF) |
                     ((uint32_t)((vb2 >> (16 * e)) & 0xFFFF) << 16);
        *(uint32_t*)(&Vt[cur ^ 1][0] + (vd0 + e) * 72 + 2 * vp) = w;
      }
    }

    // PV: O += P @ V from Vt[cur]
    __builtin_amdgcn_s_setprio(1);
#pragma unroll
    for (int n = 0; n < 4; ++n) {
      bf16x8 vb0 = *(const bf16x8*)(&Vt[cur][0] + (n * 16 + fr) * 72 + fk);
      bf16x8 vb1 = *(const bf16x8*)(&Vt[cur][0] + (n * 16 + fr) * 72 + 32 + fk);
      acc[n] = mfma16(pa0, vb0, acc[n]);
      acc[n] = mfma16(pa1, vb1, acc[n]);
    }
    __builtin_amdgcn_s_setprio(0);

    __syncthreads();   // drains K(j+1) gload_lds + Vt writes; frees bufs[cur]
  }

  // epilogue: normalize and store bf16
  float lq[4];
#pragma unroll
  for (int i = 0; i < 4; ++i) lq[i] = __shfl(lrun, fr4 + i, 64);
#pragma unroll
  for (int i = 0; i < 4; ++i) {
    float rl = 1.0f / lq[i];
    size_t t = trow0 + rg * 16 + fr4 + i;
#pragma unroll
    for (int n = 0; n < 4; ++n)
      attn[t * 2048 + h * 64 + n * 16 + fr] = (bf16)(acc[n][i] * rl);
  }
}

// ---------------- launch ----------------
extern "C" void kernel_launch(void* const* d_in, const int* in_sizes, int n_in,
                              void* d_out, int out_size, void* d_ws, size_t ws_size,
                              hipStream_t stream) {
  (void)in_sizes; (void)n_in; (void)out_size; (void)ws_size;
  const float* hs = (const float*)d_in[0];
  const float* Wq = (const float*)d_in[1];
  const float* Wk = (const float*)d_in[2];
  const float* Wv = (const float*)d_in[3];
  const float* Wo = (const float*)d_in[4];
  float* out = (float*)d_out;

  char* ws = (char*)d_ws;
  bf16* hs16 = (bf16*)(ws + 0);              // 8192*2048*2  = 33554432
  bf16* qkv  = (bf16*)(ws + 33554432);       // 8192*3072*2  = 50331648
  bf16* attn = (bf16*)(ws + 83886080);       // 8192*2048*2  = 33554432
  bf16* wq16 = (bf16*)(ws + 117440512);      // 2048*2048*2  = 8388608
  bf16* wk16 = (bf16*)(ws + 125829120);      // 512*2048*2   = 2097152
  bf16* wv16 = (bf16*)(ws + 127926272);      // 512*2048*2   = 2097152
  bf16* wo16 = (bf16*)(ws + 130023424);      // 2048*2048*2  = 8388608
  float* cosT = (float*)(ws + 138412032);    // 8192*32*4    = 1048576
  float* sinT = (float*)(ws + 139460608);    // 8192*32*4    = 1048576

  prep_all<<<27648, 256, 0, stream>>>(hs, Wq, Wk, Wv, Wo,
                                      hs16, wq16, wk16, wv16, wo16, cosT, sinT);

  // QKV projection: M=8192, N=3072, K=2048, RoPE fused; grid 256 = 1 full round
  gemm_qkv<<<dim3(32, 8), 512, 0, stream>>>(hs16, wq16, wk16, wv16, qkv, cosT, sinT);
  attn_sparse<<<dim3(128, 16), 512, 0, stream>>>(qkv, attn);
  // O projection: M=8192, N=2048, K=2048, fp32 out; grid 256 = 1 full round
  gemm_out<<<dim3(32, 8), 512, 0, stream>>>(attn, wo16, out);
}